// Round 3
// baseline (1045.332 us; speedup 1.0000x reference)
//
#include <hip/hip_runtime.h>
#include <float.h>

// ---------------------------------------------------------------------------
// SeqGraphRepNetwork. Round 2:
//  - gemm_mfma: bf16 MFMA (16x16x32) GEMMs, weights bf16 in LDS (no transpose
//    needed: W[c][k] rows are k-contiguous = B-fragment layout).
//  - attn2: key-split flash attention, 512 threads, (q,s) work items,
//    LDS partial-merge; Os aliases Ks => 50KB LDS, ~3 blocks/CU.
// ---------------------------------------------------------------------------

#define D 128
#define NHEAD 4
#define HD 32
#define MAXL 160

typedef __attribute__((ext_vector_type(8))) short short8;
typedef __attribute__((ext_vector_type(4))) float floatx4;

// ---- bf16 <-> f32 helpers (raw ushort storage, RNE) ------------------------
__device__ __forceinline__ float lo2f(unsigned u) {
    union { unsigned i; float f; } x; x.i = u << 16; return x.f;
}
__device__ __forceinline__ float hi2f(unsigned u) {
    union { unsigned i; float f; } x; x.i = u & 0xffff0000u; return x.f;
}
__device__ __forceinline__ unsigned short f2bf(float f) {
    union { float f; unsigned i; } x; x.f = f;
    unsigned r = x.i + 0x7fffu + ((x.i >> 16) & 1u);
    return (unsigned short)(r >> 16);
}
__device__ __forceinline__ unsigned pack2(float a, float b) {
    return (unsigned)f2bf(a) | ((unsigned)f2bf(b) << 16);
}
__device__ __forceinline__ float bf2f(unsigned short u) {
    union { unsigned i; float f; } x; x.i = (unsigned)u << 16; return x.f;
}

// ---- K0: c_src = a_src @ att_W, c_dst = a_dst @ att_W ----------------------
__global__ void prep_c(const float* __restrict__ att_W, const float* __restrict__ a_src,
                       const float* __restrict__ a_dst, float* __restrict__ c_src,
                       float* __restrict__ c_dst) {
    int p = threadIdx.x;  // 128 threads
    float s = 0.f, d = 0.f;
    for (int q = 0; q < D; q++) {
        float w = att_W[q * D + p];
        s += a_src[q] * w;
        d += a_dst[q] * w;
    }
    c_src[p] = s;
    c_dst[p] = d;
}

// ---- K1: t[b] = delta_dis_embs[b] . c_src ---------------------------------
__global__ void prep_t(const float* __restrict__ delta, const float* __restrict__ c_src,
                       float* __restrict__ tb) {
    int b = blockIdx.x;       // 512 buckets
    int l = threadIdx.x;      // 64 lanes
    const float* row = delta + (size_t)b * D;
    float s = row[l] * c_src[l] + row[l + 64] * c_src[l + 64];
    #pragma unroll
    for (int o = 32; o; o >>= 1) s += __shfl_down(s, o, 64);
    if (l == 0) tb[b] = s;
}

// ---- K2: convert 6 weight matrices to bf16, layout unchanged W[c][k] -------
__global__ void conv_w(const float* __restrict__ in_proj_w,
                       const float* __restrict__ out_proj_w,
                       const float* __restrict__ ffn_w1,
                       const float* __restrict__ ffn_w2,
                       unsigned short* __restrict__ wb) {
    int idx = blockIdx.x * blockDim.x + threadIdx.x;
    if (idx >= 6 * D * D) return;
    int m = idx >> 14;            // which matrix
    int within = idx & (D * D - 1);
    const float* src;
    if (m == 0) src = in_proj_w;                 // Wq
    else if (m == 1) src = in_proj_w + D * D;    // Wk
    else if (m == 2) src = in_proj_w + 2 * D * D;// Wv
    else if (m == 3) src = out_proj_w;
    else if (m == 4) src = ffn_w1;
    else src = ffn_w2;
    wb[idx] = f2bf(src[within]);
}

// ---- K3: gather x = POI[sess_idx] (bf16), s1/s2 logit dots, session starts -
__global__ void node_gather(const float* __restrict__ POI, const int* __restrict__ sess_idx,
                            const int* __restrict__ node_pos, const int* __restrict__ batch_ids,
                            const float* __restrict__ c_src, const float* __restrict__ c_dst,
                            unsigned short* __restrict__ x, float* __restrict__ s1,
                            float* __restrict__ s2, int* __restrict__ starts, int N) {
    int n = blockIdx.x * 4 + (threadIdx.x >> 6);
    if (n >= N) return;
    int lane = threadIdx.x & 63;
    int row = sess_idx[n];
    float2 v = *(const float2*)(POI + (size_t)row * D + lane * 2);
    ((unsigned*)x)[(size_t)n * 64 + lane] = pack2(v.x, v.y);
    float ps = v.x * c_src[lane * 2] + v.y * c_src[lane * 2 + 1];
    float pd = v.x * c_dst[lane * 2] + v.y * c_dst[lane * 2 + 1];
    #pragma unroll
    for (int o = 32; o; o >>= 1) {
        ps += __shfl_down(ps, o, 64);
        pd += __shfl_down(pd, o, 64);
    }
    if (lane == 0) {
        s1[n] = ps;
        s2[n] = pd;
        if (node_pos[n] == 0) starts[batch_ids[n]] = n;
    }
}

// ---- K4: H_u[n] = softmax2 blend of x[n-1], x[n+1] (bf16 in/out) -----------
__global__ void hu_k(const unsigned short* __restrict__ x, const float* __restrict__ s1,
                     const float* __restrict__ s2, const float* __restrict__ tb,
                     const int* __restrict__ edge_dist, const int* __restrict__ batch_ids,
                     const int* __restrict__ node_pos, const int* __restrict__ lengths,
                     unsigned short* __restrict__ Hu, int N) {
    int idx = blockIdx.x * 256 + threadIdx.x;
    if (idx >= N * 32) return;
    int n = idx >> 5, d4 = idx & 31;   // 4 elems per thread
    int g = batch_ids[n], pos = node_pos[n], L = lengths[g];
    bool hasF = pos > 0;          // fwd msg from n-1, edge index (n-1)-g
    bool hasB = pos < L - 1;      // bwd msg from n+1
    float la = hasF ? (s1[n] + tb[edge_dist[n - 1 - g]]) : -FLT_MAX;
    float lb = hasB ? s2[n] : -FLT_MAX;
    float m = fmaxf(la, lb);
    float ea = hasF ? expf(la - m) : 0.f;
    float eb = hasB ? expf(lb - m) : 0.f;
    float inv = 1.f / (ea + eb + 1e-16f);
    float wa = ea * inv, wb = eb * inv;
    float r0 = 0.f, r1 = 0.f, r2 = 0.f, r3 = 0.f;
    if (hasF) {
        uint2 a = ((const uint2*)x)[(size_t)(n - 1) * 32 + d4];
        r0 = wa * lo2f(a.x); r1 = wa * hi2f(a.x);
        r2 = wa * lo2f(a.y); r3 = wa * hi2f(a.y);
    }
    if (hasB) {
        uint2 b = ((const uint2*)x)[(size_t)(n + 1) * 32 + d4];
        r0 += wb * lo2f(b.x); r1 += wb * hi2f(b.x);
        r2 += wb * lo2f(b.y); r3 += wb * hi2f(b.y);
    }
    ((uint2*)Hu)[(size_t)n * 32 + d4] = make_uint2(pack2(r0, r1), pack2(r2, r3));
}

// ---- LayerNorm (optional residual add), one wave per row (bf16 in/out) -----
__global__ void ln_k(const unsigned short* __restrict__ in, const unsigned short* __restrict__ resid,
                     const float* __restrict__ g, const float* __restrict__ b,
                     unsigned short* __restrict__ out, int N) {
    int n = blockIdx.x * 4 + (threadIdx.x >> 6);
    if (n >= N) return;
    int l = threadIdx.x & 63;
    unsigned u = ((const unsigned*)in)[(size_t)n * 64 + l];
    float vx = lo2f(u), vy = hi2f(u);
    if (resid) {
        unsigned r = ((const unsigned*)resid)[(size_t)n * 64 + l];
        vx += lo2f(r); vy += hi2f(r);
    }
    float s = vx + vy;
    float ss = vx * vx + vy * vy;
    #pragma unroll
    for (int o = 32; o; o >>= 1) {
        s += __shfl_xor(s, o, 64);
        ss += __shfl_xor(ss, o, 64);
    }
    float mu = s * (1.f / D);
    float var = ss * (1.f / D) - mu * mu;
    float rinv = rsqrtf(var + 1e-8f);
    float ox = (vx - mu) * rinv * g[l * 2] + b[l * 2];
    float oy = (vy - mu) * rinv * g[l * 2 + 1] + b[l * 2 + 1];
    ((unsigned*)out)[(size_t)n * 64 + l] = pack2(ox, oy);
}

// ---- MFMA GEMM: out[M,128](bf16) = A[M,128](bf16) @ W^T + bias (+resid)(relu)
// W is bf16 [c][k] (k contiguous) = exactly the B-fragment layout for
// mfma_f32_16x16x32_bf16 (B[k][n]: lane n=lane&15, k=quad*8+j).
// Block: 256 thr = 4 waves, each wave 32 rows x 128 cols (2 m-tiles, 8 n-tiles).
__launch_bounds__(256)
__global__ void gemm_mfma(const unsigned short* __restrict__ A, const unsigned short* __restrict__ W,
                          const float* __restrict__ bias, const unsigned short* __restrict__ resid,
                          unsigned short* __restrict__ out, int M, int doRelu) {
    __shared__ unsigned short Wl[128 * 136];   // +8 ushort pad per row (16B mult)
    int t = threadIdx.x;
    for (int i = t; i < 2048; i += 256) {      // 2048 x 16B = full 32KB matrix
        int c = i >> 4, kc = (i & 15) * 8;
        *(uint4*)&Wl[c * 136 + kc] = *(const uint4*)(W + c * 128 + kc);
    }
    __syncthreads();
    int wv = t >> 6, lane = t & 63;
    int quad = lane >> 4, l16 = lane & 15;
    int rbase = blockIdx.x * 128 + wv * 32;
    floatx4 acc[2][8];
    #pragma unroll
    for (int i = 0; i < 2; i++)
        #pragma unroll
        for (int j = 0; j < 8; j++)
            acc[i][j] = (floatx4){0.f, 0.f, 0.f, 0.f};
    #pragma unroll
    for (int kk = 0; kk < 4; kk++) {
        int k0 = kk * 32;
        short8 af[2];
        #pragma unroll
        for (int mt = 0; mt < 2; mt++) {
            int r = rbase + mt * 16 + l16;
            if (r < M) af[mt] = *(const short8*)(A + (size_t)r * D + k0 + quad * 8);
            else af[mt] = (short8){0, 0, 0, 0, 0, 0, 0, 0};
        }
        #pragma unroll
        for (int nt = 0; nt < 8; nt++) {
            short8 bf = *(const short8*)&Wl[(nt * 16 + l16) * 136 + k0 + quad * 8];
            acc[0][nt] = __builtin_amdgcn_mfma_f32_16x16x32_bf16(af[0], bf, acc[0][nt], 0, 0, 0);
            acc[1][nt] = __builtin_amdgcn_mfma_f32_16x16x32_bf16(af[1], bf, acc[1][nt], 0, 0, 0);
        }
    }
    // epilogue: col=nt*16+l16, row=rbase+mt*16+quad*4+reg (m89/m91-verified C/D)
    #pragma unroll
    for (int nt = 0; nt < 8; nt++) {
        int col = nt * 16 + l16;
        float bv = bias[col];
        #pragma unroll
        for (int mt = 0; mt < 2; mt++) {
            #pragma unroll
            for (int reg = 0; reg < 4; reg++) {
                int r = rbase + mt * 16 + quad * 4 + reg;
                if (r < M) {
                    float o = acc[mt][nt][reg] + bv;
                    if (resid) o += bf2f(resid[(size_t)r * D + col]);
                    if (doRelu) o = fmaxf(o, 0.f);
                    out[(size_t)r * D + col] = f2bf(o);
                }
            }
        }
    }
}

// ---- attn2: key-split flash attention. Block=(g,h), 512 threads. -----------
// Work item = (query q, key-chunk s), ks=floor(512/L) chunks -> 87-100% lane
// utilization for all L in [64,160]. Partials (m,l,acc32) merged via LDS.
// Os aliases Ks (dead after pass 1) => 50KB LDS.
__launch_bounds__(512)
__global__ void attn2(const unsigned short* __restrict__ qb, const unsigned short* __restrict__ kb,
                      const unsigned short* __restrict__ vb, const int* __restrict__ starts,
                      const int* __restrict__ lengths, unsigned short* __restrict__ ctx) {
    __shared__ float Ks[MAXL * HD];   // 20KB; reused as Os after pass 1
    __shared__ float Vs[MAXL * HD];   // 20KB
    __shared__ float Ms[MAXL * 8];    // 5KB partial max
    __shared__ float Ls[MAXL * 8];    // 5KB partial sum
    int g = blockIdx.x, h = blockIdx.y;
    int start = starts[g], L = lengths[g];
    int t = threadIdx.x;
    for (int i = t; i < L * 4; i += 512) {     // stage K,V bf16->f32
        int p = i >> 2, d8 = (i & 3) * 8;
        size_t goff = (size_t)(start + p) * D + h * HD + d8;
        uint4 ku = *(const uint4*)(kb + goff);
        uint4 vu = *(const uint4*)(vb + goff);
        float* kd = &Ks[p * HD + d8];
        float* vd = &Vs[p * HD + d8];
        kd[0] = lo2f(ku.x); kd[1] = hi2f(ku.x); kd[2] = lo2f(ku.y); kd[3] = hi2f(ku.y);
        kd[4] = lo2f(ku.z); kd[5] = hi2f(ku.z); kd[6] = lo2f(ku.w); kd[7] = hi2f(ku.w);
        vd[0] = lo2f(vu.x); vd[1] = hi2f(vu.x); vd[2] = lo2f(vu.y); vd[3] = hi2f(vu.y);
        vd[4] = lo2f(vu.z); vd[5] = hi2f(vu.z); vd[6] = lo2f(vu.w); vd[7] = hi2f(vu.w);
    }
    __syncthreads();
    int ks = 512 / L; if (ks > 8) ks = 8;      // L in [64,160] -> ks in [3,8]
    int Lc = (L + ks - 1) / ks;
    bool act = t < L * ks;
    int q = t % L;
    int s = t / L;
    float m = -FLT_MAX, l = 0.f;
    float acc[HD];
    #pragma unroll
    for (int d = 0; d < HD; d++) acc[d] = 0.f;
    if (act) {
        float qv[HD];
        const float scale = 0.17677669529663687f;  // 1/sqrt(32)
        size_t qoff = (size_t)(start + q) * D + h * HD;
        #pragma unroll
        for (int d8 = 0; d8 < 4; d8++) {
            uint4 u = *(const uint4*)(qb + qoff + d8 * 8);
            float* qd = &qv[d8 * 8];
            qd[0] = lo2f(u.x) * scale; qd[1] = hi2f(u.x) * scale;
            qd[2] = lo2f(u.y) * scale; qd[3] = hi2f(u.y) * scale;
            qd[4] = lo2f(u.z) * scale; qd[5] = hi2f(u.z) * scale;
            qd[6] = lo2f(u.w) * scale; qd[7] = hi2f(u.w) * scale;
        }
        int k0 = s * Lc, k1 = min(L, k0 + Lc);  // (ks-1)^2 < 64 <= L => nonempty
        for (int k = k0; k < k1; k++) {
            const float4* kr = (const float4*)&Ks[k * HD];
            float sc = 0.f;
            #pragma unroll
            for (int d4 = 0; d4 < 8; d4++) {
                float4 k4 = kr[d4];
                sc += qv[4 * d4] * k4.x + qv[4 * d4 + 1] * k4.y
                    + qv[4 * d4 + 2] * k4.z + qv[4 * d4 + 3] * k4.w;
            }
            float mn = fmaxf(m, sc);
            float alpha = __expf(m - mn);   // first iter: exp(-inf)=0
            float p = __expf(sc - mn);
            l = l * alpha + p;
            const float4* vr = (const float4*)&Vs[k * HD];
            #pragma unroll
            for (int d4 = 0; d4 < 8; d4++) {
                float4 v4 = vr[d4];
                acc[4 * d4]     = acc[4 * d4]     * alpha + p * v4.x;
                acc[4 * d4 + 1] = acc[4 * d4 + 1] * alpha + p * v4.y;
                acc[4 * d4 + 2] = acc[4 * d4 + 2] * alpha + p * v4.z;
                acc[4 * d4 + 3] = acc[4 * d4 + 3] * alpha + p * v4.w;
            }
            m = mn;
        }
        Ms[q * 8 + s] = m;
        Ls[q * 8 + s] = l;
    }
    __syncthreads();          // Ks now dead -> alias as Os
    float* Os = Ks;
    for (int i = t; i < L * HD; i += 512) Os[i] = 0.f;
    __syncthreads();
    if (act) {
        float M = -FLT_MAX;
        for (int j = 0; j < ks; j++) M = fmaxf(M, Ms[q * 8 + j]);
        float lsum = 0.f;
        for (int j = 0; j < ks; j++) lsum += Ls[q * 8 + j] * __expf(Ms[q * 8 + j] - M);
        float sc = __expf(m - M) / (lsum + 1e-16f);
        #pragma unroll
        for (int d = 0; d < HD; d++) atomicAdd(&Os[q * HD + d], acc[d] * sc);
    }
    __syncthreads();
    if (t < L) {
        const float* o = &Os[t * HD];
        size_t coff = (size_t)(start + t) * D + h * HD;
        #pragma unroll
        for (int d8 = 0; d8 < 4; d8++) {
            uint4 u;
            u.x = pack2(o[8 * d8 + 0], o[8 * d8 + 1]);
            u.y = pack2(o[8 * d8 + 2], o[8 * d8 + 3]);
            u.z = pack2(o[8 * d8 + 4], o[8 * d8 + 5]);
            u.w = pack2(o[8 * d8 + 6], o[8 * d8 + 7]);
            *(uint4*)(ctx + coff + d8 * 8) = u;
        }
    }
}

// ---- masked mean pool (bf16 -> fp32 out) -----------------------------------
__global__ void pool_k(const unsigned short* __restrict__ fin, const int* __restrict__ starts,
                       const int* __restrict__ lengths, float* __restrict__ out) {
    int g = blockIdx.x, d = threadIdx.x;  // 128 threads
    int start = starts[g], L = lengths[g];
    float s = 0.f;
    for (int p = 0; p < L; p++) s += bf2f(fin[(size_t)(start + p) * D + d]);
    out[(size_t)g * D + d] = s / (float)L;
}

// ---------------------------------------------------------------------------
extern "C" void kernel_launch(void* const* d_in, const int* in_sizes, int n_in,
                              void* d_out, int out_size, void* d_ws, size_t ws_size,
                              hipStream_t stream) {
    const float* POI        = (const float*)d_in[0];
    const float* delta      = (const float*)d_in[1];
    const float* att_W      = (const float*)d_in[2];
    const float* a_src      = (const float*)d_in[3];
    const float* a_dst      = (const float*)d_in[4];
    const float* in_proj_w  = (const float*)d_in[5];
    const float* in_proj_b  = (const float*)d_in[6];
    const float* out_proj_w = (const float*)d_in[7];
    const float* out_proj_b = (const float*)d_in[8];
    const float* ln1_g      = (const float*)d_in[9];
    const float* ln1_b      = (const float*)d_in[10];
    const float* ln2_g      = (const float*)d_in[11];
    const float* ln2_b      = (const float*)d_in[12];
    const float* ffn_w1     = (const float*)d_in[13];
    const float* ffn_b1     = (const float*)d_in[14];
    const float* ffn_w2     = (const float*)d_in[15];
    const float* ffn_b2     = (const float*)d_in[16];
    const int* sess_idx     = (const int*)d_in[17];
    const int* edge_dist    = (const int*)d_in[18];
    const int* batch_ids    = (const int*)d_in[20];
    const int* node_pos     = (const int*)d_in[21];
    const int* lengths      = (const int*)d_in[22];

    int N = in_sizes[17];
    int B = in_sizes[22];

    // ---- workspace layout in BYTES, 256-aligned blocks ---------------------
    char* base = (char*)d_ws;
    size_t off = 0;
    auto alloc = [&](size_t bytes) { size_t c = off; off = (off + bytes + 255) & ~(size_t)255; return c; };
    size_t o_csrc  = alloc(D * 4);
    size_t o_cdst  = alloc(D * 4);
    size_t o_t     = alloc(512 * 4);
    size_t o_s1    = alloc((size_t)N * 4);
    size_t o_s2    = alloc((size_t)N * 4);
    size_t o_start = alloc((size_t)B * 4);
    size_t o_wb    = alloc(6 * D * D * 2);       // bf16 weights
    size_t nb      = (size_t)N * D * 2;          // one bf16 [N,128] buffer
    size_t o_A = alloc(nb);
    size_t o_B = alloc(nb);
    size_t o_C = alloc(nb);
    size_t o_D = alloc(nb);
    if (ws_size < off) return;   // diagnostic: silent fail, no GPU fault

    float* c_src = (float*)(base + o_csrc);
    float* c_dst = (float*)(base + o_cdst);
    float* tb    = (float*)(base + o_t);
    float* s1    = (float*)(base + o_s1);
    float* s2    = (float*)(base + o_s2);
    int*   starts = (int*)(base + o_start);
    unsigned short* wb = (unsigned short*)(base + o_wb);
    unsigned short* bufA = (unsigned short*)(base + o_A);
    unsigned short* bufB = (unsigned short*)(base + o_B);
    unsigned short* bufC = (unsigned short*)(base + o_C);
    unsigned short* bufD = (unsigned short*)(base + o_D);

    // ---- pipeline ----------------------------------------------------------
    prep_c<<<1, 128, 0, stream>>>(att_W, a_src, a_dst, c_src, c_dst);
    prep_t<<<512, 64, 0, stream>>>(delta, c_src, tb);
    conv_w<<<(6 * D * D + 255) / 256, 256, 0, stream>>>(in_proj_w, out_proj_w, ffn_w1, ffn_w2, wb);
    node_gather<<<(N + 3) / 4, 256, 0, stream>>>(POI, sess_idx, node_pos, batch_ids,
                                                 c_src, c_dst, bufA, s1, s2, starts, N); // x=A
    hu_k<<<(N * 32 + 255) / 256, 256, 0, stream>>>(bufA, s1, s2, tb, edge_dist, batch_ids,
                                                   node_pos, lengths, bufB, N);          // Hu=B
    ln_k<<<(N + 3) / 4, 256, 0, stream>>>(bufB, nullptr, ln1_g, ln1_b, bufC, N);         // Q=C

    int gb = (N + 127) / 128;
    gemm_mfma<<<gb, 256, 0, stream>>>(bufB, wb + 1 * 16384, in_proj_b + D,     nullptr, bufD, N, 0); // k=D
    gemm_mfma<<<gb, 256, 0, stream>>>(bufB, wb + 2 * 16384, in_proj_b + 2 * D, nullptr, bufA, N, 0); // v=A
    gemm_mfma<<<gb, 256, 0, stream>>>(bufC, wb + 0 * 16384, in_proj_b,         nullptr, bufB, N, 0); // q=B

    attn2<<<dim3(B, NHEAD), 512, 0, stream>>>(bufB, bufD, bufA, starts, lengths, bufB);  // ctx=B

    gemm_mfma<<<gb, 256, 0, stream>>>(bufB, wb + 3 * 16384, out_proj_b, nullptr, bufD, N, 0); // tmp=D
    ln_k<<<(N + 3) / 4, 256, 0, stream>>>(bufD, bufC, ln2_g, ln2_b, bufA, N);                 // out2=A
    gemm_mfma<<<gb, 256, 0, stream>>>(bufA, wb + 4 * 16384, ffn_b1, nullptr, bufC, N, 1);     // hidden=C
    gemm_mfma<<<gb, 256, 0, stream>>>(bufC, wb + 5 * 16384, ffn_b2, bufA, bufD, N, 0);        // fin=D
    pool_k<<<B, 128, 0, stream>>>(bufD, starts, lengths, (float*)d_out);
}

// Round 4
// 551.033 us; speedup vs baseline: 1.8970x; 1.8970x over previous
//
#include <hip/hip_runtime.h>
#include <float.h>

// ---------------------------------------------------------------------------
// SeqGraphRepNetwork. Round 4:
//  - attn_mfma: per-(session,head) single-wave MFMA flash attention.
//    S^T = K.Q^T (1 MFMA per 16-key tile, head-dim 32 = one K=32 contraction),
//    softmax in-register (query = lane&15 -> 2 shfl_xor), P -> LDS (A-layout),
//    O = P.V with V^T staged in LDS. No atomics, no cross-wave merge.
//  - hu_ln: H_u blend + LN1 fused (wave per row).
//  - gemm_mfma mode 2: out_proj + bias + residual + LN2 fused in epilogue.
// ---------------------------------------------------------------------------

#define D 128
#define NHEAD 4
#define HD 32
#define MAXL 160
#define MAXNK 10     // max 16-key tiles (L<=160)
#define LP 40        // Ks row pitch in bf16 (32 + 8 pad)
#define VP 168       // Vt / Pb key pitch in bf16 (160 + 8 pad)

typedef __attribute__((ext_vector_type(8))) short short8;
typedef __attribute__((ext_vector_type(4))) float floatx4;

// ---- bf16 <-> f32 helpers (raw ushort storage, RNE) ------------------------
__device__ __forceinline__ float lo2f(unsigned u) {
    union { unsigned i; float f; } x; x.i = u << 16; return x.f;
}
__device__ __forceinline__ float hi2f(unsigned u) {
    union { unsigned i; float f; } x; x.i = u & 0xffff0000u; return x.f;
}
__device__ __forceinline__ unsigned short f2bf(float f) {
    union { float f; unsigned i; } x; x.f = f;
    unsigned r = x.i + 0x7fffu + ((x.i >> 16) & 1u);
    return (unsigned short)(r >> 16);
}
__device__ __forceinline__ unsigned pack2(float a, float b) {
    return (unsigned)f2bf(a) | ((unsigned)f2bf(b) << 16);
}
__device__ __forceinline__ float bf2f(unsigned short u) {
    union { unsigned i; float f; } x; x.i = (unsigned)u << 16; return x.f;
}

// ---- K0: c_src = a_src @ att_W, c_dst = a_dst @ att_W ----------------------
__global__ void prep_c(const float* __restrict__ att_W, const float* __restrict__ a_src,
                       const float* __restrict__ a_dst, float* __restrict__ c_src,
                       float* __restrict__ c_dst) {
    int p = threadIdx.x;  // 128 threads
    float s = 0.f, d = 0.f;
    for (int q = 0; q < D; q++) {
        float w = att_W[q * D + p];
        s += a_src[q] * w;
        d += a_dst[q] * w;
    }
    c_src[p] = s;
    c_dst[p] = d;
}

// ---- K1: t[b] = delta_dis_embs[b] . c_src ---------------------------------
__global__ void prep_t(const float* __restrict__ delta, const float* __restrict__ c_src,
                       float* __restrict__ tb) {
    int b = blockIdx.x;       // 512 buckets
    int l = threadIdx.x;      // 64 lanes
    const float* row = delta + (size_t)b * D;
    float s = row[l] * c_src[l] + row[l + 64] * c_src[l + 64];
    #pragma unroll
    for (int o = 32; o; o >>= 1) s += __shfl_down(s, o, 64);
    if (l == 0) tb[b] = s;
}

// ---- K2: convert 6 weight matrices to bf16, layout unchanged W[c][k] -------
__global__ void conv_w(const float* __restrict__ in_proj_w,
                       const float* __restrict__ out_proj_w,
                       const float* __restrict__ ffn_w1,
                       const float* __restrict__ ffn_w2,
                       unsigned short* __restrict__ wb) {
    int idx = blockIdx.x * blockDim.x + threadIdx.x;
    if (idx >= 6 * D * D) return;
    int m = idx >> 14;            // which matrix
    int within = idx & (D * D - 1);
    const float* src;
    if (m == 0) src = in_proj_w;                 // Wq
    else if (m == 1) src = in_proj_w + D * D;    // Wk
    else if (m == 2) src = in_proj_w + 2 * D * D;// Wv
    else if (m == 3) src = out_proj_w;
    else if (m == 4) src = ffn_w1;
    else src = ffn_w2;
    wb[idx] = f2bf(src[within]);
}

// ---- K3: gather x = POI[sess_idx] (bf16), s1/s2 logit dots, session starts -
__global__ void node_gather(const float* __restrict__ POI, const int* __restrict__ sess_idx,
                            const int* __restrict__ node_pos, const int* __restrict__ batch_ids,
                            const float* __restrict__ c_src, const float* __restrict__ c_dst,
                            unsigned short* __restrict__ x, float* __restrict__ s1,
                            float* __restrict__ s2, int* __restrict__ starts, int N) {
    int n = blockIdx.x * 4 + (threadIdx.x >> 6);
    if (n >= N) return;
    int lane = threadIdx.x & 63;
    int row = sess_idx[n];
    float2 v = *(const float2*)(POI + (size_t)row * D + lane * 2);
    ((unsigned*)x)[(size_t)n * 64 + lane] = pack2(v.x, v.y);
    float ps = v.x * c_src[lane * 2] + v.y * c_src[lane * 2 + 1];
    float pd = v.x * c_dst[lane * 2] + v.y * c_dst[lane * 2 + 1];
    #pragma unroll
    for (int o = 32; o; o >>= 1) {
        ps += __shfl_down(ps, o, 64);
        pd += __shfl_down(pd, o, 64);
    }
    if (lane == 0) {
        s1[n] = ps;
        s2[n] = pd;
        if (node_pos[n] == 0) starts[batch_ids[n]] = n;
    }
}

// ---- K4: H_u blend + fused LN1 (wave per row) ------------------------------
__global__ void hu_ln(const unsigned short* __restrict__ x, const float* __restrict__ s1,
                      const float* __restrict__ s2, const float* __restrict__ tb,
                      const int* __restrict__ edge_dist, const int* __restrict__ batch_ids,
                      const int* __restrict__ node_pos, const int* __restrict__ lengths,
                      const float* __restrict__ g1, const float* __restrict__ b1,
                      unsigned short* __restrict__ Hu, unsigned short* __restrict__ Q, int N) {
    int n = blockIdx.x * 4 + (threadIdx.x >> 6);
    if (n >= N) return;
    int l = threadIdx.x & 63;
    int g = batch_ids[n], pos = node_pos[n], L = lengths[g];
    bool hasF = pos > 0;
    bool hasB = pos < L - 1;
    float la = hasF ? (s1[n] + tb[edge_dist[n - 1 - g]]) : -FLT_MAX;
    float lb = hasB ? s2[n] : -FLT_MAX;
    float m = fmaxf(la, lb);
    float ea = hasF ? __expf(la - m) : 0.f;
    float eb = hasB ? __expf(lb - m) : 0.f;
    float inv = 1.f / (ea + eb + 1e-16f);
    float wa = ea * inv, wb = eb * inv;
    unsigned a = hasF ? ((const unsigned*)x)[(size_t)(n - 1) * 64 + l] : 0u;
    unsigned b = hasB ? ((const unsigned*)x)[(size_t)(n + 1) * 64 + l] : 0u;
    float h0 = wa * lo2f(a) + wb * lo2f(b);
    float h1 = wa * hi2f(a) + wb * hi2f(b);
    ((unsigned*)Hu)[(size_t)n * 64 + l] = pack2(h0, h1);
    // LN1 on fp32 h (pre-rounding, matches ref closer)
    float s = h0 + h1, ss = h0 * h0 + h1 * h1;
    #pragma unroll
    for (int o = 32; o; o >>= 1) {
        s += __shfl_xor(s, o, 64);
        ss += __shfl_xor(ss, o, 64);
    }
    float mu = s * (1.f / D);
    float var = ss * (1.f / D) - mu * mu;
    float rinv = rsqrtf(var + 1e-8f);
    float q0 = (h0 - mu) * rinv * g1[l * 2] + b1[l * 2];
    float q1 = (h1 - mu) * rinv * g1[l * 2 + 1] + b1[l * 2 + 1];
    ((unsigned*)Q)[(size_t)n * 64 + l] = pack2(q0, q1);
}

// ---- MFMA GEMM: out[M,128](bf16) = A[M,128](bf16) @ W^T + bias; ------------
// mode 0: (+resid); mode 1: relu; mode 2: LN2(x + resid) fused epilogue.
__launch_bounds__(256)
__global__ void gemm_mfma(const unsigned short* __restrict__ A, const unsigned short* __restrict__ W,
                          const float* __restrict__ bias, const unsigned short* __restrict__ resid,
                          unsigned short* __restrict__ out, int M, int mode,
                          const float* __restrict__ lng, const float* __restrict__ lnb) {
    __shared__ unsigned short Wl[128 * 136];   // +8 ushort pad per row (16B mult)
    int t = threadIdx.x;
    for (int i = t; i < 2048; i += 256) {      // full 32KB matrix
        int c = i >> 4, kc = (i & 15) * 8;
        *(uint4*)&Wl[c * 136 + kc] = *(const uint4*)(W + c * 128 + kc);
    }
    __syncthreads();
    int wv = t >> 6, lane = t & 63;
    int quad = lane >> 4, l16 = lane & 15;
    int rbase = blockIdx.x * 128 + wv * 32;
    floatx4 acc[2][8];
    #pragma unroll
    for (int i = 0; i < 2; i++)
        #pragma unroll
        for (int j = 0; j < 8; j++)
            acc[i][j] = (floatx4){0.f, 0.f, 0.f, 0.f};
    #pragma unroll
    for (int kk = 0; kk < 4; kk++) {
        int k0 = kk * 32;
        short8 af[2];
        #pragma unroll
        for (int mt = 0; mt < 2; mt++) {
            int r = rbase + mt * 16 + l16;
            if (r < M) af[mt] = *(const short8*)(A + (size_t)r * D + k0 + quad * 8);
            else af[mt] = (short8){0, 0, 0, 0, 0, 0, 0, 0};
        }
        #pragma unroll
        for (int nt = 0; nt < 8; nt++) {
            short8 bf = *(const short8*)&Wl[(nt * 16 + l16) * 136 + k0 + quad * 8];
            acc[0][nt] = __builtin_amdgcn_mfma_f32_16x16x32_bf16(af[0], bf, acc[0][nt], 0, 0, 0);
            acc[1][nt] = __builtin_amdgcn_mfma_f32_16x16x32_bf16(af[1], bf, acc[1][nt], 0, 0, 0);
        }
    }
    // C/D: col = nt*16+l16, row = rbase + mt*16 + quad*4 + reg
    if (mode == 2) {
        float gv[8], bv[8], bb[8];
        #pragma unroll
        for (int nt = 0; nt < 8; nt++) {
            int col = nt * 16 + l16;
            gv[nt] = lng[col]; bv[nt] = lnb[col]; bb[nt] = bias[col];
        }
        #pragma unroll
        for (int mt = 0; mt < 2; mt++) {
            #pragma unroll
            for (int r = 0; r < 4; r++) {
                int row = rbase + mt * 16 + quad * 4 + r;
                bool ok = row < M;
                float s = 0.f, ss = 0.f;
                #pragma unroll
                for (int nt = 0; nt < 8; nt++) {
                    float v = acc[mt][nt][r] + bb[nt];
                    if (ok) v += bf2f(resid[(size_t)row * D + nt * 16 + l16]);
                    acc[mt][nt][r] = v;
                    s += v; ss += v * v;
                }
                #pragma unroll
                for (int o = 1; o < 16; o <<= 1) {   // row lives in one quad's 16 lanes
                    s += __shfl_xor(s, o, 64);
                    ss += __shfl_xor(ss, o, 64);
                }
                float mu = s * (1.f / D);
                float var = ss * (1.f / D) - mu * mu;
                float rinv = rsqrtf(var + 1e-8f);
                if (ok) {
                    #pragma unroll
                    for (int nt = 0; nt < 8; nt++)
                        out[(size_t)row * D + nt * 16 + l16] =
                            f2bf((acc[mt][nt][r] - mu) * rinv * gv[nt] + bv[nt]);
                }
            }
        }
    } else {
        #pragma unroll
        for (int nt = 0; nt < 8; nt++) {
            int col = nt * 16 + l16;
            float bv = bias[col];
            #pragma unroll
            for (int mt = 0; mt < 2; mt++) {
                #pragma unroll
                for (int reg = 0; reg < 4; reg++) {
                    int r = rbase + mt * 16 + quad * 4 + reg;
                    if (r < M) {
                        float o = acc[mt][nt][reg] + bv;
                        if (resid) o += bf2f(resid[(size_t)r * D + col]);
                        if (mode == 1) o = fmaxf(o, 0.f);
                        out[(size_t)r * D + col] = f2bf(o);
                    }
                }
            }
        }
    }
}

// ---- attn_mfma: one wave per (session, head). ------------------------------
// S^T tile = K-tile . Q-tile^T via mfma_16x16x32 (head dim 32 = 1 contraction).
// C layout: key = quad*4+reg, query = l16 -> softmax = in-lane + shfl_xor(16,32).
// P (bf16, normalized) -> LDS Pb[q][key]; O = P.V via MFMA with V^T staged.
__launch_bounds__(64)
__global__ void attn_mfma(const unsigned short* __restrict__ qb,
                          const unsigned short* __restrict__ kb,
                          const unsigned short* __restrict__ vb,
                          const int* __restrict__ starts, const int* __restrict__ lengths,
                          unsigned short* __restrict__ ctx) {
    __shared__ unsigned short Ks[MAXL * LP];   // 12.8 KB [key][dim(32) pad 40]
    __shared__ unsigned short Vt[HD * VP];     // 10.5 KB [dim][key pad 168]
    __shared__ unsigned short Pb[16 * VP];     // 5.25 KB [q][key pad 168]
    int g = blockIdx.x, h = blockIdx.y;
    int start = starts[g], L = lengths[g];
    int lane = threadIdx.x;
    int l16 = lane & 15, quad = lane >> 4;
    int nk = (L + 15) >> 4;       // 16-key tiles
    int nk2 = (L + 31) >> 5;      // 32-key chunks
    int nkeys = nk * 16;
    // stage K rows (zero pad rows)
    for (int i = lane; i < nkeys * 4; i += 64) {
        int r = i >> 2, c8 = (i & 3) * 8;
        uint4 v = make_uint4(0u, 0u, 0u, 0u);
        if (r < L) v = *(const uint4*)(kb + (size_t)(start + r) * D + h * HD + c8);
        *(uint4*)&Ks[r * LP + c8] = v;
    }
    // zero Vt and Pb (pad keys must be 0: P pad never written; V pad * P=0)
    for (int i = lane; i < HD * VP / 2; i += 64) ((unsigned*)Vt)[i] = 0u;
    for (int i = lane; i < 16 * VP / 2; i += 64) ((unsigned*)Pb)[i] = 0u;
    __syncthreads();
    // stage V transposed: Vt[dim][key]
    for (int i = lane; i < L * HD; i += 64) {
        int key = i >> 5, dim = i & 31;
        Vt[dim * VP + key] = vb[(size_t)(start + key) * D + h * HD + dim];
    }
    __syncthreads();
    const float scale = 0.17677669529663687f;  // 1/sqrt(32)
    for (int qt = 0; qt < nk; qt++) {
        int q0 = qt * 16;
        // B-frag: Q[q0+l16][quad*8..+8] from global (L1-resident across tiles)
        short8 qf = (short8){0, 0, 0, 0, 0, 0, 0, 0};
        int qrow = q0 + l16;
        if (qrow < L) qf = *(const short8*)(qb + (size_t)(start + qrow) * D + h * HD + quad * 8);
        floatx4 sacc[MAXNK];
        #pragma unroll
        for (int kt = 0; kt < MAXNK; kt++) {
            if (kt < nk) {
                short8 kf = *(const short8*)&Ks[(kt * 16 + l16) * LP + quad * 8];
                sacc[kt] = __builtin_amdgcn_mfma_f32_16x16x32_bf16(
                    kf, qf, (floatx4){0.f, 0.f, 0.f, 0.f}, 0, 0, 0);
            }
        }
        // softmax over keys for query q=l16; lane holds keys kt*16+quad*4+reg
        float m = -FLT_MAX;
        #pragma unroll
        for (int kt = 0; kt < MAXNK; kt++) {
            if (kt < nk) {
                #pragma unroll
                for (int r = 0; r < 4; r++) {
                    int key = kt * 16 + quad * 4 + r;
                    float s = (key < L) ? sacc[kt][r] * scale : -FLT_MAX;
                    sacc[kt][r] = s;
                    m = fmaxf(m, s);
                }
            }
        }
        m = fmaxf(m, __shfl_xor(m, 16));
        m = fmaxf(m, __shfl_xor(m, 32));
        float lsum = 0.f;
        #pragma unroll
        for (int kt = 0; kt < MAXNK; kt++) {
            if (kt < nk) {
                #pragma unroll
                for (int r = 0; r < 4; r++) {
                    float p = __expf(sacc[kt][r] - m);
                    sacc[kt][r] = p;
                    lsum += p;
                }
            }
        }
        lsum += __shfl_xor(lsum, 16);
        lsum += __shfl_xor(lsum, 32);
        float inv = 1.f / lsum;
        __syncthreads();   // previous tile's PV reads of Pb complete
        #pragma unroll
        for (int kt = 0; kt < MAXNK; kt++) {
            if (kt < nk) {
                *(unsigned*)&Pb[l16 * VP + kt * 16 + quad * 4] =
                    pack2(sacc[kt][0] * inv, sacc[kt][1] * inv);
                *(unsigned*)&Pb[l16 * VP + kt * 16 + quad * 4 + 2] =
                    pack2(sacc[kt][2] * inv, sacc[kt][3] * inv);
            }
        }
        __syncthreads();
        // O = P.V : A = Pb rows (q=l16), B = Vt rows (dim), contraction 32 keys
        #pragma unroll
        for (int nc = 0; nc < 2; nc++) {
            floatx4 oacc = (floatx4){0.f, 0.f, 0.f, 0.f};
            #pragma unroll
            for (int kc = 0; kc < 5; kc++) {
                if (kc < nk2) {
                    short8 pf = *(const short8*)&Pb[l16 * VP + kc * 32 + quad * 8];
                    short8 vf = *(const short8*)&Vt[(nc * 16 + l16) * VP + kc * 32 + quad * 8];
                    oacc = __builtin_amdgcn_mfma_f32_16x16x32_bf16(pf, vf, oacc, 0, 0, 0);
                }
            }
            #pragma unroll
            for (int r = 0; r < 4; r++) {
                int qr = q0 + quad * 4 + r;
                if (qr < L)
                    ctx[(size_t)(start + qr) * D + h * HD + nc * 16 + l16] = f2bf(oacc[r]);
            }
        }
    }
}

// ---- masked mean pool (bf16 -> fp32 out) -----------------------------------
__global__ void pool_k(const unsigned short* __restrict__ fin, const int* __restrict__ starts,
                       const int* __restrict__ lengths, float* __restrict__ out) {
    int g = blockIdx.x, d = threadIdx.x;  // 128 threads
    int start = starts[g], L = lengths[g];
    float s0 = 0.f, s1 = 0.f, s2 = 0.f, s3 = 0.f;
    int p = 0;
    for (; p + 4 <= L; p += 4) {
        s0 += bf2f(fin[(size_t)(start + p) * D + d]);
        s1 += bf2f(fin[(size_t)(start + p + 1) * D + d]);
        s2 += bf2f(fin[(size_t)(start + p + 2) * D + d]);
        s3 += bf2f(fin[(size_t)(start + p + 3) * D + d]);
    }
    for (; p < L; p++) s0 += bf2f(fin[(size_t)(start + p) * D + d]);
    out[(size_t)g * D + d] = (s0 + s1 + s2 + s3) / (float)L;
}

// ---------------------------------------------------------------------------
extern "C" void kernel_launch(void* const* d_in, const int* in_sizes, int n_in,
                              void* d_out, int out_size, void* d_ws, size_t ws_size,
                              hipStream_t stream) {
    const float* POI        = (const float*)d_in[0];
    const float* delta      = (const float*)d_in[1];
    const float* att_W      = (const float*)d_in[2];
    const float* a_src      = (const float*)d_in[3];
    const float* a_dst      = (const float*)d_in[4];
    const float* in_proj_w  = (const float*)d_in[5];
    const float* in_proj_b  = (const float*)d_in[6];
    const float* out_proj_w = (const float*)d_in[7];
    const float* out_proj_b = (const float*)d_in[8];
    const float* ln1_g      = (const float*)d_in[9];
    const float* ln1_b      = (const float*)d_in[10];
    const float* ln2_g      = (const float*)d_in[11];
    const float* ln2_b      = (const float*)d_in[12];
    const float* ffn_w1     = (const float*)d_in[13];
    const float* ffn_b1     = (const float*)d_in[14];
    const float* ffn_w2     = (const float*)d_in[15];
    const float* ffn_b2     = (const float*)d_in[16];
    const int* sess_idx     = (const int*)d_in[17];
    const int* edge_dist    = (const int*)d_in[18];
    const int* batch_ids    = (const int*)d_in[20];
    const int* node_pos     = (const int*)d_in[21];
    const int* lengths      = (const int*)d_in[22];

    int N = in_sizes[17];
    int B = in_sizes[22];

    // ---- workspace layout in BYTES, 256-aligned blocks ---------------------
    char* base = (char*)d_ws;
    size_t off = 0;
    auto alloc = [&](size_t bytes) { size_t c = off; off = (off + bytes + 255) & ~(size_t)255; return c; };
    size_t o_csrc  = alloc(D * 4);
    size_t o_cdst  = alloc(D * 4);
    size_t o_t     = alloc(512 * 4);
    size_t o_s1    = alloc((size_t)N * 4);
    size_t o_s2    = alloc((size_t)N * 4);
    size_t o_start = alloc((size_t)B * 4);
    size_t o_wb    = alloc(6 * D * D * 2);       // bf16 weights
    size_t nb      = (size_t)N * D * 2;          // one bf16 [N,128] buffer
    size_t o_A = alloc(nb);
    size_t o_B = alloc(nb);
    size_t o_C = alloc(nb);
    size_t o_D = alloc(nb);
    if (ws_size < off) return;   // diagnostic: silent fail, no GPU fault

    float* c_src = (float*)(base + o_csrc);
    float* c_dst = (float*)(base + o_cdst);
    float* tb    = (float*)(base + o_t);
    float* s1    = (float*)(base + o_s1);
    float* s2    = (float*)(base + o_s2);
    int*   starts = (int*)(base + o_start);
    unsigned short* wb = (unsigned short*)(base + o_wb);
    unsigned short* bufA = (unsigned short*)(base + o_A);
    unsigned short* bufB = (unsigned short*)(base + o_B);
    unsigned short* bufC = (unsigned short*)(base + o_C);
    unsigned short* bufD = (unsigned short*)(base + o_D);

    // ---- pipeline ----------------------------------------------------------
    prep_c<<<1, 128, 0, stream>>>(att_W, a_src, a_dst, c_src, c_dst);
    prep_t<<<512, 64, 0, stream>>>(delta, c_src, tb);
    conv_w<<<(6 * D * D + 255) / 256, 256, 0, stream>>>(in_proj_w, out_proj_w, ffn_w1, ffn_w2, wb);
    node_gather<<<(N + 3) / 4, 256, 0, stream>>>(POI, sess_idx, node_pos, batch_ids,
                                                 c_src, c_dst, bufA, s1, s2, starts, N); // x=A
    hu_ln<<<(N + 3) / 4, 256, 0, stream>>>(bufA, s1, s2, tb, edge_dist, batch_ids,
                                           node_pos, lengths, ln1_g, ln1_b,
                                           bufB, bufC, N);                               // Hu=B, Q=C

    int gb = (N + 127) / 128;
    gemm_mfma<<<gb, 256, 0, stream>>>(bufB, wb + 1 * 16384, in_proj_b + D,     nullptr, bufD, N, 0, nullptr, nullptr); // k=D
    gemm_mfma<<<gb, 256, 0, stream>>>(bufB, wb + 2 * 16384, in_proj_b + 2 * D, nullptr, bufA, N, 0, nullptr, nullptr); // v=A
    gemm_mfma<<<gb, 256, 0, stream>>>(bufC, wb + 0 * 16384, in_proj_b,         nullptr, bufB, N, 0, nullptr, nullptr); // q=B

    attn_mfma<<<dim3(B, NHEAD), 64, 0, stream>>>(bufB, bufD, bufA, starts, lengths, bufB); // ctx=B (safe alias)

    gemm_mfma<<<gb, 256, 0, stream>>>(bufB, wb + 3 * 16384, out_proj_b, bufC, bufD, N, 2, ln2_g, ln2_b); // out2=D (LN2 fused)
    gemm_mfma<<<gb, 256, 0, stream>>>(bufD, wb + 4 * 16384, ffn_b1, nullptr, bufC, N, 1, nullptr, nullptr); // hidden=C
    gemm_mfma<<<gb, 256, 0, stream>>>(bufC, wb + 5 * 16384, ffn_b2, bufD, bufA, N, 0, nullptr, nullptr);    // fin=A
    pool_k<<<B, 128, 0, stream>>>(bufA, starts, lengths, (float*)d_out);
}

// Round 5
// 431.471 us; speedup vs baseline: 2.4227x; 1.2771x over previous
//
#include <hip/hip_runtime.h>
#include <float.h>

// ---------------------------------------------------------------------------
// SeqGraphRepNetwork. Round 5:
//  - qkv_fused: Hu A-frags in regs once; one LDS weight buffer restaged 3x
//    (Wk, Wv, W'q). Q-path refolded: q = rinv*(Hu@W'q^T - mu*u) + z.
//  - ffn_fused: hidden stays on-chip (LDS buffer reused W1 -> Ht -> W2).
//  - outproj_ln2: out_proj + Q-residual recomputed from Hu + LN2, fused.
//  - attn3: K-frags hoisted to registers (no Ks LDS), 16KB LDS -> ~9 blk/CU.
// ---------------------------------------------------------------------------

#define D 128
#define NHEAD 4
#define HD 32
#define MAXL 160
#define MAXNK 10     // max 16-key tiles (L<=160)
#define VP 168       // Vt / Pb key pitch in ushorts (160 + 8; 336B = 21*16)
#define WP 136       // weight LDS pitch in ushorts (272B = 17*16)

typedef __attribute__((ext_vector_type(8))) short short8;
typedef __attribute__((ext_vector_type(4))) float floatx4;

// ---- bf16 <-> f32 helpers (raw ushort storage, RNE) ------------------------
__device__ __forceinline__ float lo2f(unsigned u) {
    union { unsigned i; float f; } x; x.i = u << 16; return x.f;
}
__device__ __forceinline__ float hi2f(unsigned u) {
    union { unsigned i; float f; } x; x.i = u & 0xffff0000u; return x.f;
}
__device__ __forceinline__ unsigned short f2bf(float f) {
    union { float f; unsigned i; } x; x.f = f;
    unsigned r = x.i + 0x7fffu + ((x.i >> 16) & 1u);
    return (unsigned short)(r >> 16);
}
__device__ __forceinline__ unsigned pack2(float a, float b) {
    return (unsigned)f2bf(a) | ((unsigned)f2bf(b) << 16);
}
__device__ __forceinline__ float bf2f(unsigned short u) {
    union { unsigned i; float f; } x; x.i = (unsigned)u << 16; return x.f;
}

// ---- K0: c_src = a_src @ att_W, c_dst = a_dst @ att_W ----------------------
__global__ void prep_c(const float* __restrict__ att_W, const float* __restrict__ a_src,
                       const float* __restrict__ a_dst, float* __restrict__ c_src,
                       float* __restrict__ c_dst) {
    int p = threadIdx.x;  // 128 threads
    float s = 0.f, d = 0.f;
    for (int q = 0; q < D; q++) {
        float w = att_W[q * D + p];
        s += a_src[q] * w;
        d += a_dst[q] * w;
    }
    c_src[p] = s;
    c_dst[p] = d;
}

// ---- K1: t[b] = delta_dis_embs[b] . c_src ---------------------------------
__global__ void prep_t(const float* __restrict__ delta, const float* __restrict__ c_src,
                       float* __restrict__ tb) {
    int b = blockIdx.x;
    int l = threadIdx.x;      // 64 lanes
    const float* row = delta + (size_t)b * D;
    float s = row[l] * c_src[l] + row[l + 64] * c_src[l + 64];
    #pragma unroll
    for (int o = 32; o; o >>= 1) s += __shfl_down(s, o, 64);
    if (l == 0) tb[b] = s;
}

// ---- K2: bf16 weights. slot0 = W'q (Wq*g1), 1=Wk, 2=Wv, 3=Wo, 4=W1, 5=W2 ---
__global__ void conv_w2(const float* __restrict__ in_proj_w,
                        const float* __restrict__ out_proj_w,
                        const float* __restrict__ ffn_w1,
                        const float* __restrict__ ffn_w2,
                        const float* __restrict__ ln1_g,
                        unsigned short* __restrict__ wb) {
    int idx = blockIdx.x * blockDim.x + threadIdx.x;
    if (idx >= 6 * D * D) return;
    int m = idx >> 14;
    int within = idx & (D * D - 1);
    float v;
    if (m == 0) v = in_proj_w[within] * ln1_g[within & (D - 1)];
    else if (m == 1) v = in_proj_w[D * D + within];
    else if (m == 2) v = in_proj_w[2 * D * D + within];
    else if (m == 3) v = out_proj_w[within];
    else if (m == 4) v = ffn_w1[within];
    else v = ffn_w2[within];
    wb[idx] = f2bf(v);
}

// ---- K2b: u[c] = g1.Wq[c,:], z[c] = b1.Wq[c,:] + bq[c] ---------------------
__global__ void prep_uz(const float* __restrict__ in_proj_w, const float* __restrict__ in_proj_b,
                        const float* __restrict__ g1, const float* __restrict__ b1,
                        float* __restrict__ u, float* __restrict__ z) {
    int c = threadIdx.x;  // 128 threads
    float su = 0.f, sz = 0.f;
    for (int k = 0; k < D; k++) {
        float w = in_proj_w[c * D + k];
        su += g1[k] * w;
        sz += b1[k] * w;
    }
    u[c] = su;
    z[c] = sz + in_proj_b[c];
}

// ---- K3: gather x = POI[sess_idx] (bf16), s1/s2 logit dots, session starts -
__global__ void node_gather(const float* __restrict__ POI, const int* __restrict__ sess_idx,
                            const int* __restrict__ node_pos, const int* __restrict__ batch_ids,
                            const float* __restrict__ c_src, const float* __restrict__ c_dst,
                            unsigned short* __restrict__ x, float* __restrict__ s1,
                            float* __restrict__ s2, int* __restrict__ starts, int N) {
    int n = blockIdx.x * 4 + (threadIdx.x >> 6);
    if (n >= N) return;
    int lane = threadIdx.x & 63;
    int row = sess_idx[n];
    float2 v = *(const float2*)(POI + (size_t)row * D + lane * 2);
    ((unsigned*)x)[(size_t)n * 64 + lane] = pack2(v.x, v.y);
    float ps = v.x * c_src[lane * 2] + v.y * c_src[lane * 2 + 1];
    float pd = v.x * c_dst[lane * 2] + v.y * c_dst[lane * 2 + 1];
    #pragma unroll
    for (int o = 32; o; o >>= 1) {
        ps += __shfl_down(ps, o, 64);
        pd += __shfl_down(pd, o, 64);
    }
    if (lane == 0) {
        s1[n] = ps;
        s2[n] = pd;
        if (node_pos[n] == 0) starts[batch_ids[n]] = n;
    }
}

// ---- K4: H_u blend + LN1 stats (mu, rinv) per row --------------------------
__global__ void hu_ln2(const unsigned short* __restrict__ x, const float* __restrict__ s1,
                       const float* __restrict__ s2, const float* __restrict__ tb,
                       const int* __restrict__ edge_dist, const int* __restrict__ batch_ids,
                       const int* __restrict__ node_pos, const int* __restrict__ lengths,
                       unsigned short* __restrict__ Hu, float* __restrict__ muv,
                       float* __restrict__ rinvv, int N) {
    int n = blockIdx.x * 4 + (threadIdx.x >> 6);
    if (n >= N) return;
    int l = threadIdx.x & 63;
    int g = batch_ids[n], pos = node_pos[n], L = lengths[g];
    bool hasF = pos > 0;
    bool hasB = pos < L - 1;
    float la = hasF ? (s1[n] + tb[edge_dist[n - 1 - g]]) : -FLT_MAX;
    float lb = hasB ? s2[n] : -FLT_MAX;
    float m = fmaxf(la, lb);
    float ea = hasF ? __expf(la - m) : 0.f;
    float eb = hasB ? __expf(lb - m) : 0.f;
    float inv = 1.f / (ea + eb + 1e-16f);
    float wa = ea * inv, wb = eb * inv;
    unsigned a = hasF ? ((const unsigned*)x)[(size_t)(n - 1) * 64 + l] : 0u;
    unsigned b = hasB ? ((const unsigned*)x)[(size_t)(n + 1) * 64 + l] : 0u;
    float h0 = wa * lo2f(a) + wb * lo2f(b);
    float h1 = wa * hi2f(a) + wb * hi2f(b);
    ((unsigned*)Hu)[(size_t)n * 64 + l] = pack2(h0, h1);
    float s = h0 + h1, ss = h0 * h0 + h1 * h1;
    #pragma unroll
    for (int o = 32; o; o >>= 1) {
        s += __shfl_xor(s, o, 64);
        ss += __shfl_xor(ss, o, 64);
    }
    float mu = s * (1.f / D);
    float var = ss * (1.f / D) - mu * mu;
    if (l == 0) {
        muv[n] = mu;
        rinvv[n] = rsqrtf(var + 1e-8f);
    }
}

// ---- qkv_fused: reads Hu A-frags once; LDS weight buffer restaged 3x -------
// pass 0: Wk -> k (+bias); pass 1: Wv -> v (+bias);
// pass 2: W'q -> q = rinv*(acc - mu*u[col]) + z[col].
__launch_bounds__(256)
__global__ void qkv_fused(const unsigned short* __restrict__ Hu, const unsigned short* __restrict__ wb,
                          const float* __restrict__ in_proj_b, const float* __restrict__ u,
                          const float* __restrict__ z, const float* __restrict__ muv,
                          const float* __restrict__ rinvv,
                          unsigned short* __restrict__ qo, unsigned short* __restrict__ ko,
                          unsigned short* __restrict__ vo, int M) {
    __shared__ unsigned short Wl[128 * WP];
    int t = threadIdx.x;
    int wv = t >> 6, lane = t & 63;
    int quad = lane >> 4, l16 = lane & 15;
    int rbase = blockIdx.x * 128 + wv * 32;
    // A-frags once (held across all 3 passes)
    short8 af[2][4];
    #pragma unroll
    for (int mt = 0; mt < 2; mt++) {
        int r = rbase + mt * 16 + l16;
        #pragma unroll
        for (int kk = 0; kk < 4; kk++) {
            if (r < M) af[mt][kk] = *(const short8*)(Hu + (size_t)r * D + kk * 32 + quad * 8);
            else af[mt][kk] = (short8){0, 0, 0, 0, 0, 0, 0, 0};
        }
    }
    for (int p = 0; p < 3; p++) {
        const unsigned short* W = wb + (p == 0 ? 1 : p == 1 ? 2 : 0) * (D * D);
        for (int i = t; i < 2048; i += 256) {
            int c = i >> 4, kc = (i & 15) * 8;
            *(uint4*)&Wl[c * WP + kc] = *(const uint4*)(W + c * 128 + kc);
        }
        __syncthreads();
        floatx4 acc[2][8];
        #pragma unroll
        for (int i = 0; i < 2; i++)
            #pragma unroll
            for (int j = 0; j < 8; j++) acc[i][j] = (floatx4){0.f, 0.f, 0.f, 0.f};
        #pragma unroll
        for (int kk = 0; kk < 4; kk++) {
            #pragma unroll
            for (int nt = 0; nt < 8; nt++) {
                short8 bf = *(const short8*)&Wl[(nt * 16 + l16) * WP + kk * 32 + quad * 8];
                acc[0][nt] = __builtin_amdgcn_mfma_f32_16x16x32_bf16(af[0][kk], bf, acc[0][nt], 0, 0, 0);
                acc[1][nt] = __builtin_amdgcn_mfma_f32_16x16x32_bf16(af[1][kk], bf, acc[1][nt], 0, 0, 0);
            }
        }
        __syncthreads();   // all waves done reading Wl before next restage
        if (p < 2) {
            unsigned short* out = p == 0 ? ko : vo;
            const float* bias = in_proj_b + (p == 0 ? D : 2 * D);
            #pragma unroll
            for (int nt = 0; nt < 8; nt++) {
                int col = nt * 16 + l16;
                float bv = bias[col];
                #pragma unroll
                for (int mt = 0; mt < 2; mt++)
                    #pragma unroll
                    for (int r = 0; r < 4; r++) {
                        int row = rbase + mt * 16 + quad * 4 + r;
                        if (row < M) out[(size_t)row * D + col] = f2bf(acc[mt][nt][r] + bv);
                    }
            }
        } else {
            float uc[8], zc[8];
            #pragma unroll
            for (int nt = 0; nt < 8; nt++) {
                uc[nt] = u[nt * 16 + l16];
                zc[nt] = z[nt * 16 + l16];
            }
            #pragma unroll
            for (int mt = 0; mt < 2; mt++)
                #pragma unroll
                for (int r = 0; r < 4; r++) {
                    int row = rbase + mt * 16 + quad * 4 + r;
                    if (row < M) {
                        float mr = muv[row], rr = rinvv[row];
                        #pragma unroll
                        for (int nt = 0; nt < 8; nt++)
                            qo[(size_t)row * D + nt * 16 + l16] =
                                f2bf(rr * (acc[mt][nt][r] - mr * uc[nt]) + zc[nt]);
                    }
                }
        }
    }
}

// ---- attn3: one wave per (session, head); K-frags in registers -------------
__launch_bounds__(64)
__global__ void attn3(const unsigned short* __restrict__ qb,
                      const unsigned short* __restrict__ kb,
                      const unsigned short* __restrict__ vb,
                      const int* __restrict__ starts, const int* __restrict__ lengths,
                      unsigned short* __restrict__ ctx) {
    __shared__ unsigned short Vt[HD * VP];     // 10.5 KB [dim][key]
    __shared__ unsigned short Pb[16 * VP];     // 5.25 KB [q][key]
    int g = blockIdx.x, h = blockIdx.y;
    int start = starts[g], L = lengths[g];
    int lane = threadIdx.x;
    int l16 = lane & 15, quad = lane >> 4;
    int nk = (L + 15) >> 4;
    int nk2 = (L + 31) >> 5;
    // zero Vt + Pb (pad keys must be exactly 0: avoids NaN in MFMA)
    for (int i = lane; i < (HD * VP) / 2; i += 64) ((unsigned*)Vt)[i] = 0u;
    for (int i = lane; i < (16 * VP) / 2; i += 64) ((unsigned*)Pb)[i] = 0u;
    // K fragments hoisted into registers (A-layout: m=key=l16, k=dim=quad*8+j)
    short8 kf[MAXNK];
    #pragma unroll
    for (int kt = 0; kt < MAXNK; kt++) {
        kf[kt] = (short8){0, 0, 0, 0, 0, 0, 0, 0};
        if (kt < nk) {
            int r = kt * 16 + l16;
            if (r < L) kf[kt] = *(const short8*)(kb + (size_t)(start + r) * D + h * HD + quad * 8);
        }
    }
    __syncthreads();
    // stage V transposed: lane reads uint4 (8 dims of one key), scatters 8 ushorts
    for (int i = lane; i < L * 4; i += 64) {
        int key = i >> 2, dg = (i & 3) * 8;
        uint4 vu = *(const uint4*)(vb + (size_t)(start + key) * D + h * HD + dg);
        Vt[(dg + 0) * VP + key] = (unsigned short)(vu.x & 0xffff);
        Vt[(dg + 1) * VP + key] = (unsigned short)(vu.x >> 16);
        Vt[(dg + 2) * VP + key] = (unsigned short)(vu.y & 0xffff);
        Vt[(dg + 3) * VP + key] = (unsigned short)(vu.y >> 16);
        Vt[(dg + 4) * VP + key] = (unsigned short)(vu.z & 0xffff);
        Vt[(dg + 5) * VP + key] = (unsigned short)(vu.z >> 16);
        Vt[(dg + 6) * VP + key] = (unsigned short)(vu.w & 0xffff);
        Vt[(dg + 7) * VP + key] = (unsigned short)(vu.w >> 16);
    }
    __syncthreads();
    const float scale = 0.17677669529663687f;  // 1/sqrt(32)
    for (int qt = 0; qt < nk; qt++) {
        int q0 = qt * 16;
        short8 qf = (short8){0, 0, 0, 0, 0, 0, 0, 0};
        int qrow = q0 + l16;
        if (qrow < L) qf = *(const short8*)(qb + (size_t)(start + qrow) * D + h * HD + quad * 8);
        floatx4 sacc[MAXNK];
        #pragma unroll
        for (int kt = 0; kt < MAXNK; kt++)
            if (kt < nk)
                sacc[kt] = __builtin_amdgcn_mfma_f32_16x16x32_bf16(
                    kf[kt], qf, (floatx4){0.f, 0.f, 0.f, 0.f}, 0, 0, 0);
        // softmax for query q=l16; this lane holds keys kt*16+quad*4+r
        float m = -FLT_MAX;
        #pragma unroll
        for (int kt = 0; kt < MAXNK; kt++)
            if (kt < nk) {
                #pragma unroll
                for (int r = 0; r < 4; r++) {
                    int key = kt * 16 + quad * 4 + r;
                    float s = (key < L) ? sacc[kt][r] * scale : -FLT_MAX;
                    sacc[kt][r] = s;
                    m = fmaxf(m, s);
                }
            }
        m = fmaxf(m, __shfl_xor(m, 16));
        m = fmaxf(m, __shfl_xor(m, 32));
        float lsum = 0.f;
        #pragma unroll
        for (int kt = 0; kt < MAXNK; kt++)
            if (kt < nk) {
                #pragma unroll
                for (int r = 0; r < 4; r++) {
                    float p = __expf(sacc[kt][r] - m);
                    sacc[kt][r] = p;
                    lsum += p;
                }
            }
        lsum += __shfl_xor(lsum, 16);
        lsum += __shfl_xor(lsum, 32);
        float inv = 1.f / lsum;
        __syncthreads();   // previous tile's PV reads of Pb complete
        #pragma unroll
        for (int kt = 0; kt < MAXNK; kt++)
            if (kt < nk) {
                *(unsigned*)&Pb[l16 * VP + kt * 16 + quad * 4] =
                    pack2(sacc[kt][0] * inv, sacc[kt][1] * inv);
                *(unsigned*)&Pb[l16 * VP + kt * 16 + quad * 4 + 2] =
                    pack2(sacc[kt][2] * inv, sacc[kt][3] * inv);
            }
        __syncthreads();
        #pragma unroll
        for (int nc = 0; nc < 2; nc++) {
            floatx4 oacc = (floatx4){0.f, 0.f, 0.f, 0.f};
            #pragma unroll
            for (int kc = 0; kc < 5; kc++)
                if (kc < nk2) {
                    short8 pf = *(const short8*)&Pb[l16 * VP + kc * 32 + quad * 8];
                    short8 vf = *(const short8*)&Vt[(nc * 16 + l16) * VP + kc * 32 + quad * 8];
                    oacc = __builtin_amdgcn_mfma_f32_16x16x32_bf16(pf, vf, oacc, 0, 0, 0);
                }
            #pragma unroll
            for (int r = 0; r < 4; r++) {
                int qr = q0 + quad * 4 + r;
                if (qr < L)
                    ctx[(size_t)(start + qr) * D + h * HD + nc * 16 + l16] = f2bf(oacc[r]);
            }
        }
    }
}

// ---- outproj_ln2: out2 = LN2( ctx@Wo^T + bo + Q ), Q recomputed from Hu ----
__launch_bounds__(256)
__global__ void outproj_ln2(const unsigned short* __restrict__ ctx, const unsigned short* __restrict__ W,
                            const float* __restrict__ bo, const unsigned short* __restrict__ Hu,
                            const float* __restrict__ muv, const float* __restrict__ rinvv,
                            const float* __restrict__ g1, const float* __restrict__ b1,
                            const float* __restrict__ g2, const float* __restrict__ b2,
                            unsigned short* __restrict__ out, int M) {
    __shared__ unsigned short Wl[128 * WP];
    int t = threadIdx.x;
    for (int i = t; i < 2048; i += 256) {
        int c = i >> 4, kc = (i & 15) * 8;
        *(uint4*)&Wl[c * WP + kc] = *(const uint4*)(W + c * 128 + kc);
    }
    __syncthreads();
    int wv = t >> 6, lane = t & 63;
    int quad = lane >> 4, l16 = lane & 15;
    int rbase = blockIdx.x * 128 + wv * 32;
    floatx4 acc[2][8];
    #pragma unroll
    for (int i = 0; i < 2; i++)
        #pragma unroll
        for (int j = 0; j < 8; j++) acc[i][j] = (floatx4){0.f, 0.f, 0.f, 0.f};
    #pragma unroll
    for (int kk = 0; kk < 4; kk++) {
        short8 af[2];
        #pragma unroll
        for (int mt = 0; mt < 2; mt++) {
            int r = rbase + mt * 16 + l16;
            if (r < M) af[mt] = *(const short8*)(ctx + (size_t)r * D + kk * 32 + quad * 8);
            else af[mt] = (short8){0, 0, 0, 0, 0, 0, 0, 0};
        }
        #pragma unroll
        for (int nt = 0; nt < 8; nt++) {
            short8 bf = *(const short8*)&Wl[(nt * 16 + l16) * WP + kk * 32 + quad * 8];
            acc[0][nt] = __builtin_amdgcn_mfma_f32_16x16x32_bf16(af[0], bf, acc[0][nt], 0, 0, 0);
            acc[1][nt] = __builtin_amdgcn_mfma_f32_16x16x32_bf16(af[1], bf, acc[1][nt], 0, 0, 0);
        }
    }
    float g1c[8], b1c[8], boc[8], g2c[8], b2c[8];
    #pragma unroll
    for (int nt = 0; nt < 8; nt++) {
        int col = nt * 16 + l16;
        g1c[nt] = g1[col]; b1c[nt] = b1[col]; boc[nt] = bo[col];
        g2c[nt] = g2[col]; b2c[nt] = b2[col];
    }
    #pragma unroll
    for (int mt = 0; mt < 2; mt++) {
        #pragma unroll
        for (int r = 0; r < 4; r++) {
            int row = rbase + mt * 16 + quad * 4 + r;
            bool ok = row < M;
            float mr = ok ? muv[row] : 0.f;
            float rr = ok ? rinvv[row] : 0.f;
            float s = 0.f, ss = 0.f;
            #pragma unroll
            for (int nt = 0; nt < 8; nt++) {
                float huv = ok ? bf2f(Hu[(size_t)row * D + nt * 16 + l16]) : 0.f;
                float qv = (huv - mr) * rr * g1c[nt] + b1c[nt];
                float v = acc[mt][nt][r] + boc[nt] + qv;
                acc[mt][nt][r] = v;
                s += v; ss += v * v;
            }
            #pragma unroll
            for (int o = 1; o < 16; o <<= 1) {   // row spans one quad's 16 lanes
                s += __shfl_xor(s, o, 64);
                ss += __shfl_xor(ss, o, 64);
            }
            float mu = s * (1.f / D);
            float var = ss * (1.f / D) - mu * mu;
            float rinv = rsqrtf(var + 1e-8f);
            if (ok) {
                #pragma unroll
                for (int nt = 0; nt < 8; nt++)
                    out[(size_t)row * D + nt * 16 + l16] =
                        f2bf((acc[mt][nt][r] - mu) * rinv * g2c[nt] + b2c[nt]);
            }
        }
    }
}

// ---- ffn_fused: fin = out2 + relu(out2@W1^T+b1)@W2^T + b2 ------------------
// hidden never leaves the CU: Wl holds W1, then hidden (Ht), then W2.
__launch_bounds__(256)
__global__ void ffn_fused(const unsigned short* __restrict__ out2, const unsigned short* __restrict__ W1,
                          const float* __restrict__ b1f, const unsigned short* __restrict__ W2,
                          const float* __restrict__ b2f, unsigned short* __restrict__ fin, int M) {
    __shared__ unsigned short Wl[128 * WP];
    int t = threadIdx.x;
    int wv = t >> 6, lane = t & 63;
    int quad = lane >> 4, l16 = lane & 15;
    int rbase = blockIdx.x * 128 + wv * 32;
    int lbase = wv * 32;                     // block-local row base
    for (int i = t; i < 2048; i += 256) {    // stage W1
        int c = i >> 4, kc = (i & 15) * 8;
        *(uint4*)&Wl[c * WP + kc] = *(const uint4*)(W1 + c * 128 + kc);
    }
    short8 af[2][4];
    #pragma unroll
    for (int mt = 0; mt < 2; mt++) {
        int r = rbase + mt * 16 + l16;
        #pragma unroll
        for (int kk = 0; kk < 4; kk++) {
            if (r < M) af[mt][kk] = *(const short8*)(out2 + (size_t)r * D + kk * 32 + quad * 8);
            else af[mt][kk] = (short8){0, 0, 0, 0, 0, 0, 0, 0};
        }
    }
    __syncthreads();
    floatx4 acc[2][8];
    #pragma unroll
    for (int i = 0; i < 2; i++)
        #pragma unroll
        for (int j = 0; j < 8; j++) acc[i][j] = (floatx4){0.f, 0.f, 0.f, 0.f};
    #pragma unroll
    for (int kk = 0; kk < 4; kk++)
        #pragma unroll
        for (int nt = 0; nt < 8; nt++) {
            short8 bf = *(const short8*)&Wl[(nt * 16 + l16) * WP + kk * 32 + quad * 8];
            acc[0][nt] = __builtin_amdgcn_mfma_f32_16x16x32_bf16(af[0][kk], bf, acc[0][nt], 0, 0, 0);
            acc[1][nt] = __builtin_amdgcn_mfma_f32_16x16x32_bf16(af[1][kk], bf, acc[1][nt], 0, 0, 0);
        }
    __syncthreads();   // done reading W1
    // hidden = relu(acc + b1) -> bf16 -> Wl as Ht[localrow][WP]
    #pragma unroll
    for (int nt = 0; nt < 8; nt++) {
        int col = nt * 16 + l16;
        float bv = b1f[col];
        #pragma unroll
        for (int mt = 0; mt < 2; mt++)
            #pragma unroll
            for (int r = 0; r < 4; r++)
                Wl[(lbase + mt * 16 + quad * 4 + r) * WP + col] =
                    f2bf(fmaxf(acc[mt][nt][r] + bv, 0.f));
    }
    __syncthreads();
    short8 af2[2][4];
    #pragma unroll
    for (int mt = 0; mt < 2; mt++)
        #pragma unroll
        for (int kk = 0; kk < 4; kk++)
            af2[mt][kk] = *(const short8*)&Wl[(lbase + mt * 16 + l16) * WP + kk * 32 + quad * 8];
    __syncthreads();
    for (int i = t; i < 2048; i += 256) {    // stage W2
        int c = i >> 4, kc = (i & 15) * 8;
        *(uint4*)&Wl[c * WP + kc] = *(const uint4*)(W2 + c * 128 + kc);
    }
    __syncthreads();
    #pragma unroll
    for (int i = 0; i < 2; i++)
        #pragma unroll
        for (int j = 0; j < 8; j++) acc[i][j] = (floatx4){0.f, 0.f, 0.f, 0.f};
    #pragma unroll
    for (int kk = 0; kk < 4; kk++)
        #pragma unroll
        for (int nt = 0; nt < 8; nt++) {
            short8 bf = *(const short8*)&Wl[(nt * 16 + l16) * WP + kk * 32 + quad * 8];
            acc[0][nt] = __builtin_amdgcn_mfma_f32_16x16x32_bf16(af2[0][kk], bf, acc[0][nt], 0, 0, 0);
            acc[1][nt] = __builtin_amdgcn_mfma_f32_16x16x32_bf16(af2[1][kk], bf, acc[1][nt], 0, 0, 0);
        }
    #pragma unroll
    for (int nt = 0; nt < 8; nt++) {
        int col = nt * 16 + l16;
        float bv = b2f[col];
        #pragma unroll
        for (int mt = 0; mt < 2; mt++)
            #pragma unroll
            for (int r = 0; r < 4; r++) {
                int row = rbase + mt * 16 + quad * 4 + r;
                if (row < M)
                    fin[(size_t)row * D + col] =
                        f2bf(acc[mt][nt][r] + bv + bf2f(out2[(size_t)row * D + col]));
            }
    }
}

// ---- masked mean pool (bf16 -> fp32 out) -----------------------------------
__global__ void pool_k(const unsigned short* __restrict__ fin, const int* __restrict__ starts,
                       const int* __restrict__ lengths, float* __restrict__ out) {
    int g = blockIdx.x, d = threadIdx.x;  // 128 threads
    int start = starts[g], L = lengths[g];
    float s0 = 0.f, s1 = 0.f, s2 = 0.f, s3 = 0.f;
    int p = 0;
    for (; p + 4 <= L; p += 4) {
        s0 += bf2f(fin[(size_t)(start + p) * D + d]);
        s1 += bf2f(fin[(size_t)(start + p + 1) * D + d]);
        s2 += bf2f(fin[(size_t)(start + p + 2) * D + d]);
        s3 += bf2f(fin[(size_t)(start + p + 3) * D + d]);
    }
    for (; p < L; p++) s0 += bf2f(fin[(size_t)(start + p) * D + d]);
    out[(size_t)g * D + d] = (s0 + s1 + s2 + s3) / (float)L;
}

// ---------------------------------------------------------------------------
extern "C" void kernel_launch(void* const* d_in, const int* in_sizes, int n_in,
                              void* d_out, int out_size, void* d_ws, size_t ws_size,
                              hipStream_t stream) {
    const float* POI        = (const float*)d_in[0];
    const float* delta      = (const float*)d_in[1];
    const float* att_W      = (const float*)d_in[2];
    const float* a_src      = (const float*)d_in[3];
    const float* a_dst      = (const float*)d_in[4];
    const float* in_proj_w  = (const float*)d_in[5];
    const float* in_proj_b  = (const float*)d_in[6];
    const float* out_proj_w = (const float*)d_in[7];
    const float* out_proj_b = (const float*)d_in[8];
    const float* ln1_g      = (const float*)d_in[9];
    const float* ln1_b      = (const float*)d_in[10];
    const float* ln2_g      = (const float*)d_in[11];
    const float* ln2_b      = (const float*)d_in[12];
    const float* ffn_w1     = (const float*)d_in[13];
    const float* ffn_b1     = (const float*)d_in[14];
    const float* ffn_w2     = (const float*)d_in[15];
    const float* ffn_b2     = (const float*)d_in[16];
    const int* sess_idx     = (const int*)d_in[17];
    const int* edge_dist    = (const int*)d_in[18];
    const int* batch_ids    = (const int*)d_in[20];
    const int* node_pos     = (const int*)d_in[21];
    const int* lengths      = (const int*)d_in[22];

    int N = in_sizes[17];
    int B = in_sizes[22];

    // ---- workspace layout in BYTES, 256-aligned blocks ---------------------
    char* base = (char*)d_ws;
    size_t off = 0;
    auto alloc = [&](size_t bytes) { size_t c = off; off = (off + bytes + 255) & ~(size_t)255; return c; };
    size_t o_csrc  = alloc(D * 4);
    size_t o_cdst  = alloc(D * 4);
    size_t o_t     = alloc(512 * 4);
    size_t o_s1    = alloc((size_t)N * 4);
    size_t o_s2    = alloc((size_t)N * 4);
    size_t o_start = alloc((size_t)B * 4);
    size_t o_mu    = alloc((size_t)N * 4);
    size_t o_ri    = alloc((size_t)N * 4);
    size_t o_u     = alloc(D * 4);
    size_t o_z     = alloc(D * 4);
    size_t o_wb    = alloc(6 * D * D * 2);       // bf16 weights
    size_t nb      = (size_t)N * D * 2;          // one bf16 [N,128] buffer
    size_t o_A = alloc(nb);
    size_t o_B = alloc(nb);
    size_t o_C = alloc(nb);
    size_t o_D = alloc(nb);
    if (ws_size < off) return;   // diagnostic: silent fail, no GPU fault

    float* c_src = (float*)(base + o_csrc);
    float* c_dst = (float*)(base + o_cdst);
    float* tb    = (float*)(base + o_t);
    float* s1    = (float*)(base + o_s1);
    float* s2    = (float*)(base + o_s2);
    int*   starts = (int*)(base + o_start);
    float* muv   = (float*)(base + o_mu);
    float* rinvv = (float*)(base + o_ri);
    float* u     = (float*)(base + o_u);
    float* z     = (float*)(base + o_z);
    unsigned short* wb = (unsigned short*)(base + o_wb);
    unsigned short* bufA = (unsigned short*)(base + o_A);
    unsigned short* bufB = (unsigned short*)(base + o_B);
    unsigned short* bufC = (unsigned short*)(base + o_C);
    unsigned short* bufD = (unsigned short*)(base + o_D);

    // ---- pipeline ----------------------------------------------------------
    prep_c<<<1, 128, 0, stream>>>(att_W, a_src, a_dst, c_src, c_dst);
    prep_t<<<512, 64, 0, stream>>>(delta, c_src, tb);
    conv_w2<<<(6 * D * D + 255) / 256, 256, 0, stream>>>(in_proj_w, out_proj_w, ffn_w1, ffn_w2, ln1_g, wb);
    prep_uz<<<1, 128, 0, stream>>>(in_proj_w, in_proj_b, ln1_g, ln1_b, u, z);
    node_gather<<<(N + 3) / 4, 256, 0, stream>>>(POI, sess_idx, node_pos, batch_ids,
                                                 c_src, c_dst, bufA, s1, s2, starts, N); // x=A
    hu_ln2<<<(N + 3) / 4, 256, 0, stream>>>(bufA, s1, s2, tb, edge_dist, batch_ids,
                                            node_pos, lengths, bufB, muv, rinvv, N);     // Hu=B

    int gb = (N + 127) / 128;
    qkv_fused<<<gb, 256, 0, stream>>>(bufB, wb, in_proj_b, u, z, muv, rinvv,
                                      bufC, bufD, bufA, N);         // q=C, k=D, v=A

    attn3<<<dim3(B, NHEAD), 64, 0, stream>>>(bufC, bufD, bufA, starts, lengths, bufC); // ctx=C

    outproj_ln2<<<gb, 256, 0, stream>>>(bufC, wb + 3 * D * D, out_proj_b, bufB, muv, rinvv,
                                        ln1_g, ln1_b, ln2_g, ln2_b, bufD, N);          // out2=D
    ffn_fused<<<gb, 256, 0, stream>>>(bufD, wb + 4 * D * D, ffn_b1, wb + 5 * D * D, ffn_b2,
                                      bufA, N);                                        // fin=A
    pool_k<<<B, 128, 0, stream>>>(bufA, starts, lengths, (float*)d_out);
}